// Round 3
// baseline (293.848 us; speedup 1.0000x reference)
//
#include <hip/hip_runtime.h>
#include <stdint.h>
#include <stddef.h>

#define B_ 2048
#define D_ 4096
#define E_ 512
#define N_ 8192
#define SPLITK 8

typedef unsigned short ushort_t;
typedef __attribute__((ext_vector_type(8))) short short8;
typedef __attribute__((ext_vector_type(4))) float floatx4;
typedef __attribute__((ext_vector_type(4))) unsigned short ushort4_t;

__device__ __forceinline__ void async_load16(const void* g, void* l) {
  __builtin_amdgcn_global_load_lds((__attribute__((address_space(1))) void*)(g),
                                   (__attribute__((address_space(3))) void*)(l), 16, 0, 0);
}

__device__ __forceinline__ ushort_t f2bf(float f) {
  unsigned int u = __float_as_uint(f);
  unsigned int r = (u + 0x7fffu + ((u >> 16) & 1u)) >> 16;
  return (ushort_t)r;
}
__device__ __forceinline__ float bf2f(ushort_t h) {
  return __uint_as_float(((unsigned int)h) << 16);
}

// ---------------- BatchNorm stats (float4) ----------------
// grid (D/1024, 64), 256 thr: each thread accumulates 4 cols over 32 rows.
__global__ __launch_bounds__(256) void bn_partial(const float* __restrict__ vf,
                                                  float* __restrict__ psum,
                                                  float* __restrict__ psq) {
  int d4 = blockIdx.x * 256 + threadIdx.x;
  int chunk = blockIdx.y;
  floatx4 s = {0.f, 0.f, 0.f, 0.f}, q = {0.f, 0.f, 0.f, 0.f};
  int r0 = chunk * 32;
  for (int r = r0; r < r0 + 32; ++r) {
    floatx4 v = ((const floatx4*)(vf + (size_t)r * D_))[d4];
    s += v; q += v * v;
  }
  ((floatx4*)(psum + (size_t)chunk * D_))[d4] = s;
  ((floatx4*)(psq  + (size_t)chunk * D_))[d4] = q;
}

__global__ __launch_bounds__(256) void bn_finalize(const float* __restrict__ psum,
                                                   const float* __restrict__ psq,
                                                   const float* __restrict__ gamma,
                                                   const float* __restrict__ beta,
                                                   float* __restrict__ scale,
                                                   float* __restrict__ shift) {
  int d4 = blockIdx.x * 256 + threadIdx.x;   // 0..1023
  floatx4 s = {0.f, 0.f, 0.f, 0.f}, q = {0.f, 0.f, 0.f, 0.f};
  for (int c = 0; c < 64; ++c) {
    s += ((const floatx4*)(psum + (size_t)c * D_))[d4];
    q += ((const floatx4*)(psq  + (size_t)c * D_))[d4];
  }
  floatx4 g = ((const floatx4*)gamma)[d4];
  floatx4 bt = ((const floatx4*)beta)[d4];
  floatx4 sc, sh;
#pragma unroll
  for (int j = 0; j < 4; ++j) {
    float mean = s[j] * (1.0f / B_);
    float var  = q[j] * (1.0f / B_) - mean * mean;
    float scj  = g[j] * rsqrtf(var + 1e-5f);
    sc[j] = scj;
    sh[j] = bt[j] - mean * scj;
  }
  ((floatx4*)scale)[d4] = sc;
  ((floatx4*)shift)[d4] = sh;
}

// ---------------- fused: p_e cosine + vfn bf16 cast (one wave per row) ----------------
__global__ __launch_bounds__(256) void pe_cast(const float* __restrict__ vf,
                                               const float* __restrict__ p,
                                               const float* __restrict__ scale,
                                               const float* __restrict__ shift,
                                               ushort_t* __restrict__ vfn,
                                               float* __restrict__ pe) {
  int wv = threadIdx.x >> 6, l = threadIdx.x & 63;
  int v = blockIdx.x * 4 + wv;
  const floatx4* vf4 = (const floatx4*)(vf + (size_t)v * D_);
  const floatx4* p4  = (const floatx4*)(p  + (size_t)v * D_);
  const floatx4* sc4 = (const floatx4*)scale;
  const floatx4* sh4 = (const floatx4*)shift;
  ushort_t* vrow = vfn + (size_t)v * D_;
  float sd = 0.f, sa = 0.f, sb = 0.f;
#pragma unroll 4
  for (int k = 0; k < 16; ++k) {
    int i = l + 64 * k;
    floatx4 x = vf4[i], y = p4[i], s = sc4[i], t = sh4[i];
    ushort4_t o;
#pragma unroll
    for (int j = 0; j < 4; ++j) {
      float xn = x[j] * s[j] + t[j];
      o[j] = f2bf(xn);
      sd += xn * y[j]; sa += xn * xn; sb += y[j] * y[j];
    }
    *(ushort4_t*)(vrow + i * 4) = o;
  }
  for (int off = 32; off; off >>= 1) {
    sd += __shfl_down(sd, off); sa += __shfl_down(sa, off); sb += __shfl_down(sb, off);
  }
  if (l == 0) {
    float na = fmaxf(sqrtf(sa), 1e-8f), nb = fmaxf(sqrtf(sb), 1e-8f);
    pe[v] = sd / (na * nb);
  }
}

// ---------------- prep: W cast + n_wfs cast + inv norms (fused) ----------------
// blocks [0,2048): W float4 cast; blocks [2048,4096): 4 n_wfs rows each (wave/row).
__global__ __launch_bounds__(256) void prep_kernel(const float* __restrict__ W,
                                                   const float* __restrict__ nw,
                                                   ushort_t* __restrict__ wb,
                                                   ushort_t* __restrict__ nwb,
                                                   float* __restrict__ inv_nw) {
  int bid = blockIdx.x;
  if (bid < 2048) {
    size_t i = ((size_t)bid * 256 + threadIdx.x) * 4;
    floatx4 x = *(const floatx4*)(W + i);
    ushort4_t o;
#pragma unroll
    for (int j = 0; j < 4; ++j) o[j] = f2bf(x[j]);
    *(ushort4_t*)(wb + i) = o;
  } else {
    int wv = threadIdx.x >> 6, l = threadIdx.x & 63;
    int n = (bid - 2048) * 4 + wv;
    const floatx4* src = (const floatx4*)(nw + (size_t)n * E_);
    ushort4_t* dst = (ushort4_t*)(nwb + (size_t)n * E_);
    float s = 0.f;
#pragma unroll
    for (int k = 0; k < 2; ++k) {
      floatx4 x = src[l + 64 * k];
      ushort4_t o;
#pragma unroll
      for (int j = 0; j < 4; ++j) { o[j] = f2bf(x[j]); s += x[j] * x[j]; }
      dst[l + 64 * k] = o;
    }
    for (int off = 32; off; off >>= 1) s += __shfl_down(s, off);
    if (l == 0) inv_nw[n] = 1.f / fmaxf(sqrtf(s), 1e-8f);
  }
}

// ---------------- MFMA gemm core ----------------
// Verified gfx950 16x16x32 bf16 layout: a-frag A[m=lane&15][k=quad*8+j],
// b-frag Bt[n=lane&15][k=quad*8+j], C/D: col=lane&15, row=quad*4+reg.
template <int BM, int BN, int BK, int WCOLS, int MT, int NT>
__device__ __forceinline__ void gemm_core(const ushort_t* __restrict__ A,
                                          const ushort_t* __restrict__ Bt, int K,
                                          int kb, int ke, int bm0, int bn0,
                                          ushort_t* As, ushort_t* Bs,
                                          floatx4 (&acc)[MT][NT]) {
  const int tid = threadIdx.x, w = tid >> 6, l = tid & 63;
  constexpr int ISS_A = BM * BK / 2048;   // 256 threads x 8 bf16 per issue
  constexpr int ISS_B = BN * BK / 2048;
  const int wr = w / WCOLS, wc = w % WCOLS;
  const int m16 = l & 15, q = l >> 4;

  for (int k0 = kb; k0 < ke; k0 += BK) {
#pragma unroll
    for (int i = 0; i < ISS_A; ++i) {
      int e = i * 2048 + tid * 8;
      int row = e / BK, col = e % BK;
      async_load16(A + (size_t)(bm0 + row) * K + (k0 + col), &As[i * 2048 + w * 512]);
    }
#pragma unroll
    for (int i = 0; i < ISS_B; ++i) {
      int e = i * 2048 + tid * 8;
      int row = e / BK, col = e % BK;
      async_load16(Bt + (size_t)(bn0 + row) * K + (k0 + col), &Bs[i * 2048 + w * 512]);
    }
    __syncthreads();
#pragma unroll
    for (int kc = 0; kc < BK / 32; ++kc) {
      short8 af[MT], bf[NT];
#pragma unroll
      for (int i = 0; i < MT; ++i)
        af[i] = *(const short8*)&As[(wr * (MT * 16) + i * 16 + m16) * BK + kc * 32 + q * 8];
#pragma unroll
      for (int j = 0; j < NT; ++j)
        bf[j] = *(const short8*)&Bs[(wc * (NT * 16) + j * 16 + m16) * BK + kc * 32 + q * 8];
#pragma unroll
      for (int i = 0; i < MT; ++i)
#pragma unroll
        for (int j = 0; j < NT; ++j)
          acc[i][j] = __builtin_amdgcn_mfma_f32_16x16x32_bf16(af[i], bf[j], acc[i][j], 0, 0, 0);
    }
    __syncthreads();
  }
}

// GEMM1 split-K: partial[s] = vfn @ W^T over K-chunk s. 128x64 tiles, grid (8,16,8)=1024.
__global__ __launch_bounds__(256) void gemm1_splitk(const ushort_t* __restrict__ A,
                                                    const ushort_t* __restrict__ Bt,
                                                    float* __restrict__ partial) {
  __shared__ __align__(16) ushort_t As[128 * 64];
  __shared__ __align__(16) ushort_t Bs[64 * 64];
  floatx4 acc[4][2] = {};
  int bm0 = blockIdx.y * 128, bn0 = blockIdx.x * 64, s = blockIdx.z;
  int kb = s * (D_ / SPLITK);
  gemm_core<128, 64, 64, 2, 4, 2>(A, Bt, D_, kb, kb + D_ / SPLITK, bm0, bn0, As, Bs, acc);
  int tid = threadIdx.x, w = tid >> 6, l = tid & 63, m16 = l & 15, q = l >> 4;
  int wr = w >> 1, wc = w & 1;
  float* out = partial + (size_t)s * B_ * E_;
#pragma unroll
  for (int i = 0; i < 4; ++i)
#pragma unroll
    for (int j = 0; j < 2; ++j) {
      int col = bn0 + wc * 32 + j * 16 + m16;
#pragma unroll
      for (int r = 0; r < 4; ++r) {
        int row = bm0 + wr * 64 + i * 16 + q * 4 + r;
        out[(size_t)row * E_ + col] = acc[i][j][r];
      }
    }
}

// Reduce splits + bias + ReLU + bf16 cast + row inv-norm. One block (128 thr) per row.
__global__ __launch_bounds__(128) void gemm1_reduce(const float* __restrict__ partial,
                                                    const float* __restrict__ bias,
                                                    ushort_t* __restrict__ emb,
                                                    float* __restrict__ inv_emb) {
  int row = blockIdx.x, t = threadIdx.x;
  floatx4 v = {0.f, 0.f, 0.f, 0.f};
#pragma unroll
  for (int s = 0; s < SPLITK; ++s)
    v += *(const floatx4*)&partial[(size_t)s * B_ * E_ + (size_t)row * E_ + t * 4];
  floatx4 bb = *(const floatx4*)&bias[t * 4];
  ushort4_t o;
  float sumsq = 0.f;
#pragma unroll
  for (int j = 0; j < 4; ++j) {
    float f = fmaxf(v[j] + bb[j], 0.f);
    o[j] = f2bf(f);
    float fb = bf2f(o[j]);          // norm of the bf16-rounded emb (matches gemm2 input)
    sumsq += fb * fb;
  }
  *(ushort4_t*)(emb + (size_t)row * E_ + t * 4) = o;
  for (int off = 32; off; off >>= 1) sumsq += __shfl_down(sumsq, off);
  __shared__ float r2[2];
  if ((t & 63) == 0) r2[t >> 6] = sumsq;
  __syncthreads();
  if (t == 0) inv_emb[row] = 1.f / fmaxf(sqrtf(r2[0] + r2[1]), 1e-8f);
}

// GEMM2: n_e = (emb @ nw^T) * inv_emb[row] * inv_nw[col]; also fills p_e_stack.
__global__ __launch_bounds__(256) void gemm2_kernel(const ushort_t* __restrict__ A,
                                                    const ushort_t* __restrict__ Bt,
                                                    const float* __restrict__ inv_a,
                                                    const float* __restrict__ inv_b,
                                                    const float* __restrict__ pe,
                                                    float* __restrict__ out) {
  __shared__ __align__(16) ushort_t As[128 * 64];
  __shared__ __align__(16) ushort_t Bs[128 * 64];
  floatx4 acc[4][4] = {};
  int bm0 = blockIdx.y * 128, bn0 = blockIdx.x * 128;
  gemm_core<128, 128, 64, 2, 4, 4>(A, Bt, E_, 0, E_, bm0, bn0, As, Bs, acc);
  int tid = threadIdx.x, w = tid >> 6, l = tid & 63, m16 = l & 15, q = l >> 4;
  int wr = w >> 1, wc = w & 1;
  float* out2 = out + (size_t)B_ * N_;
  float ibv[4];
#pragma unroll
  for (int j = 0; j < 4; ++j) ibv[j] = inv_b[bn0 + wc * 64 + j * 16 + m16];
#pragma unroll
  for (int i = 0; i < 4; ++i)
#pragma unroll
    for (int r = 0; r < 4; ++r) {
      int row = bm0 + wr * 64 + i * 16 + q * 4 + r;
      float ia = inv_a[row];
      float pv = pe[row];
      size_t base = (size_t)row * N_ + bn0 + wc * 64 + m16;
#pragma unroll
      for (int j = 0; j < 4; ++j) {
        out[base + j * 16]  = acc[i][j][r] * ia * ibv[j];
        out2[base + j * 16] = pv;
      }
    }
}

extern "C" void kernel_launch(void* const* d_in, const int* in_sizes, int n_in,
                              void* d_out, int out_size, void* d_ws, size_t ws_size,
                              hipStream_t stream) {
  (void)in_sizes; (void)n_in; (void)out_size; (void)ws_size;
  const float* vf    = (const float*)d_in[0];
  const float* p_wfs = (const float*)d_in[1];
  const float* n_wfs = (const float*)d_in[2];
  const float* gamma = (const float*)d_in[3];
  const float* beta  = (const float*)d_in[4];
  const float* W     = (const float*)d_in[5];
  const float* bias  = (const float*)d_in[6];
  float* out = (float*)d_out;

  char* ws = (char*)d_ws;
  float* psum    = (float*)ws;  ws += (size_t)64 * D_ * 4;
  float* psq     = (float*)ws;  ws += (size_t)64 * D_ * 4;
  float* scale   = (float*)ws;  ws += (size_t)D_ * 4;
  float* shift   = (float*)ws;  ws += (size_t)D_ * 4;
  float* pe      = (float*)ws;  ws += (size_t)B_ * 4;
  float* inv_nw  = (float*)ws;  ws += (size_t)N_ * 4;
  float* inv_emb = (float*)ws;  ws += (size_t)B_ * 4;
  float* partial = (float*)ws;  ws += (size_t)SPLITK * B_ * E_ * 4;
  ushort_t* vfn  = (ushort_t*)ws;  ws += (size_t)B_ * D_ * 2;
  ushort_t* wb   = (ushort_t*)ws;  ws += (size_t)E_ * D_ * 2;
  ushort_t* nwb  = (ushort_t*)ws;  ws += (size_t)N_ * E_ * 2;
  ushort_t* emb  = (ushort_t*)ws;  ws += (size_t)B_ * E_ * 2;

  bn_partial<<<dim3(D_ / 1024, 64), 256, 0, stream>>>(vf, psum, psq);
  bn_finalize<<<D_ / 1024, 256, 0, stream>>>(psum, psq, gamma, beta, scale, shift);
  pe_cast<<<B_ / 4, 256, 0, stream>>>(vf, p_wfs, scale, shift, vfn, pe);
  prep_kernel<<<2048 + N_ / 4, 256, 0, stream>>>(W, n_wfs, wb, nwb, inv_nw);
  gemm1_splitk<<<dim3(E_ / 64, B_ / 128, SPLITK), 256, 0, stream>>>(vfn, wb, partial);
  gemm1_reduce<<<B_, 128, 0, stream>>>(partial, bias, emb, inv_emb);
  gemm2_kernel<<<dim3(N_ / 128, B_ / 128), 256, 0, stream>>>(emb, nwb, inv_emb, inv_nw, pe, out);
}

// Round 4
// 281.375 us; speedup vs baseline: 1.0443x; 1.0443x over previous
//
#include <hip/hip_runtime.h>
#include <stdint.h>
#include <stddef.h>

#define B_ 2048
#define D_ 4096
#define E_ 512
#define N_ 8192
#define SPLITK 4

typedef unsigned short ushort_t;
typedef __attribute__((ext_vector_type(8))) short short8;
typedef __attribute__((ext_vector_type(4))) float floatx4;
typedef __attribute__((ext_vector_type(4))) unsigned short ushort4_t;

__device__ __forceinline__ void async_load16(const void* g, void* l) {
  __builtin_amdgcn_global_load_lds((__attribute__((address_space(1))) void*)(g),
                                   (__attribute__((address_space(3))) void*)(l), 16, 0, 0);
}

__device__ __forceinline__ ushort_t f2bf(float f) {
  unsigned int u = __float_as_uint(f);
  unsigned int r = (u + 0x7fffu + ((u >> 16) & 1u)) >> 16;
  return (ushort_t)r;
}
__device__ __forceinline__ float bf2f(ushort_t h) {
  return __uint_as_float(((unsigned int)h) << 16);
}

// ---------------- BatchNorm stats (float4) ----------------
__global__ __launch_bounds__(256) void bn_partial(const float* __restrict__ vf,
                                                  float* __restrict__ psum,
                                                  float* __restrict__ psq) {
  int d4 = blockIdx.x * 256 + threadIdx.x;
  int chunk = blockIdx.y;
  floatx4 s = {0.f, 0.f, 0.f, 0.f}, q = {0.f, 0.f, 0.f, 0.f};
  int r0 = chunk * 32;
  for (int r = r0; r < r0 + 32; ++r) {
    floatx4 v = ((const floatx4*)(vf + (size_t)r * D_))[d4];
    s += v; q += v * v;
  }
  ((floatx4*)(psum + (size_t)chunk * D_))[d4] = s;
  ((floatx4*)(psq  + (size_t)chunk * D_))[d4] = q;
}

__global__ __launch_bounds__(256) void bn_finalize(const float* __restrict__ psum,
                                                   const float* __restrict__ psq,
                                                   const float* __restrict__ gamma,
                                                   const float* __restrict__ beta,
                                                   float* __restrict__ scale,
                                                   float* __restrict__ shift) {
  int d4 = blockIdx.x * 256 + threadIdx.x;   // 0..1023
  floatx4 s = {0.f, 0.f, 0.f, 0.f}, q = {0.f, 0.f, 0.f, 0.f};
  for (int c = 0; c < 64; ++c) {
    s += ((const floatx4*)(psum + (size_t)c * D_))[d4];
    q += ((const floatx4*)(psq  + (size_t)c * D_))[d4];
  }
  floatx4 g = ((const floatx4*)gamma)[d4];
  floatx4 bt = ((const floatx4*)beta)[d4];
  floatx4 sc, sh;
#pragma unroll
  for (int j = 0; j < 4; ++j) {
    float mean = s[j] * (1.0f / B_);
    float var  = q[j] * (1.0f / B_) - mean * mean;
    float scj  = g[j] * rsqrtf(var + 1e-5f);
    sc[j] = scj;
    sh[j] = bt[j] - mean * scj;
  }
  ((floatx4*)scale)[d4] = sc;
  ((floatx4*)shift)[d4] = sh;
}

// ---------------- fused: p_e cosine + vfn bf16 cast (one wave per row) ----------------
__global__ __launch_bounds__(256) void pe_cast(const float* __restrict__ vf,
                                               const float* __restrict__ p,
                                               const float* __restrict__ scale,
                                               const float* __restrict__ shift,
                                               ushort_t* __restrict__ vfn,
                                               float* __restrict__ pe) {
  int wv = threadIdx.x >> 6, l = threadIdx.x & 63;
  int v = blockIdx.x * 4 + wv;
  const floatx4* vf4 = (const floatx4*)(vf + (size_t)v * D_);
  const floatx4* p4  = (const floatx4*)(p  + (size_t)v * D_);
  const floatx4* sc4 = (const floatx4*)scale;
  const floatx4* sh4 = (const floatx4*)shift;
  ushort_t* vrow = vfn + (size_t)v * D_;
  float sd = 0.f, sa = 0.f, sb = 0.f;
#pragma unroll 4
  for (int k = 0; k < 16; ++k) {
    int i = l + 64 * k;
    floatx4 x = vf4[i], y = p4[i], s = sc4[i], t = sh4[i];
    ushort4_t o;
#pragma unroll
    for (int j = 0; j < 4; ++j) {
      float xn = x[j] * s[j] + t[j];
      o[j] = f2bf(xn);
      sd += xn * y[j]; sa += xn * xn; sb += y[j] * y[j];
    }
    *(ushort4_t*)(vrow + i * 4) = o;
  }
  for (int off = 32; off; off >>= 1) {
    sd += __shfl_down(sd, off); sa += __shfl_down(sa, off); sb += __shfl_down(sb, off);
  }
  if (l == 0) {
    float na = fmaxf(sqrtf(sa), 1e-8f), nb = fmaxf(sqrtf(sb), 1e-8f);
    pe[v] = sd / (na * nb);
  }
}

// ---------------- prep: W cast + n_wfs cast + inv norms (fused) ----------------
__global__ __launch_bounds__(256) void prep_kernel(const float* __restrict__ W,
                                                   const float* __restrict__ nw,
                                                   ushort_t* __restrict__ wb,
                                                   ushort_t* __restrict__ nwb,
                                                   float* __restrict__ inv_nw) {
  int bid = blockIdx.x;
  if (bid < 2048) {
    size_t i = ((size_t)bid * 256 + threadIdx.x) * 4;
    floatx4 x = *(const floatx4*)(W + i);
    ushort4_t o;
#pragma unroll
    for (int j = 0; j < 4; ++j) o[j] = f2bf(x[j]);
    *(ushort4_t*)(wb + i) = o;
  } else {
    int wv = threadIdx.x >> 6, l = threadIdx.x & 63;
    int n = (bid - 2048) * 4 + wv;
    const floatx4* src = (const floatx4*)(nw + (size_t)n * E_);
    ushort4_t* dst = (ushort4_t*)(nwb + (size_t)n * E_);
    float s = 0.f;
#pragma unroll
    for (int k = 0; k < 2; ++k) {
      floatx4 x = src[l + 64 * k];
      ushort4_t o;
#pragma unroll
      for (int j = 0; j < 4; ++j) { o[j] = f2bf(x[j]); s += x[j] * x[j]; }
      dst[l + 64 * k] = o;
    }
    for (int off = 32; off; off >>= 1) s += __shfl_down(s, off);
    if (l == 0) inv_nw[n] = 1.f / fmaxf(sqrtf(s), 1e-8f);
  }
}

// ---------------- MFMA gemm core ----------------
// Verified gfx950 16x16x32 bf16 layout: a-frag A[m=lane&15][k=quad*8+j],
// b-frag Bt[n=lane&15][k=quad*8+j], C/D: col=lane&15, row=quad*4+reg.
template <int BM, int BN, int BK, int WCOLS, int MT, int NT>
__device__ __forceinline__ void gemm_core(const ushort_t* __restrict__ A,
                                          const ushort_t* __restrict__ Bt, int K,
                                          int kb, int ke, int bm0, int bn0,
                                          ushort_t* As, ushort_t* Bs,
                                          floatx4 (&acc)[MT][NT]) {
  const int tid = threadIdx.x, w = tid >> 6, l = tid & 63;
  constexpr int ISS_A = BM * BK / 2048;   // 256 threads x 8 bf16 per issue
  constexpr int ISS_B = BN * BK / 2048;
  const int wr = w / WCOLS, wc = w % WCOLS;
  const int m16 = l & 15, q = l >> 4;

  for (int k0 = kb; k0 < ke; k0 += BK) {
#pragma unroll
    for (int i = 0; i < ISS_A; ++i) {
      int e = i * 2048 + tid * 8;
      int row = e / BK, col = e % BK;
      async_load16(A + (size_t)(bm0 + row) * K + (k0 + col), &As[i * 2048 + w * 512]);
    }
#pragma unroll
    for (int i = 0; i < ISS_B; ++i) {
      int e = i * 2048 + tid * 8;
      int row = e / BK, col = e % BK;
      async_load16(Bt + (size_t)(bn0 + row) * K + (k0 + col), &Bs[i * 2048 + w * 512]);
    }
    __syncthreads();
#pragma unroll
    for (int kc = 0; kc < BK / 32; ++kc) {
      short8 af[MT], bf[NT];
#pragma unroll
      for (int i = 0; i < MT; ++i)
        af[i] = *(const short8*)&As[(wr * (MT * 16) + i * 16 + m16) * BK + kc * 32 + q * 8];
#pragma unroll
      for (int j = 0; j < NT; ++j)
        bf[j] = *(const short8*)&Bs[(wc * (NT * 16) + j * 16 + m16) * BK + kc * 32 + q * 8];
#pragma unroll
      for (int i = 0; i < MT; ++i)
#pragma unroll
        for (int j = 0; j < NT; ++j)
          acc[i][j] = __builtin_amdgcn_mfma_f32_16x16x32_bf16(af[i], bf[j], acc[i][j], 0, 0, 0);
    }
    __syncthreads();
  }
}

// GEMM1 split-K: partial[s] = vfn @ W^T over K-chunk s. 128x64 tiles, grid (8,16,4)=512.
__global__ __launch_bounds__(256, 2) void gemm1_splitk(const ushort_t* __restrict__ A,
                                                       const ushort_t* __restrict__ Bt,
                                                       float* __restrict__ partial) {
  __shared__ __align__(16) ushort_t As[128 * 64];
  __shared__ __align__(16) ushort_t Bs[64 * 64];
  floatx4 acc[4][2] = {};
  int bm0 = blockIdx.y * 128, bn0 = blockIdx.x * 64, s = blockIdx.z;
  int kb = s * (D_ / SPLITK);
  gemm_core<128, 64, 64, 2, 4, 2>(A, Bt, D_, kb, kb + D_ / SPLITK, bm0, bn0, As, Bs, acc);
  int tid = threadIdx.x, w = tid >> 6, l = tid & 63, m16 = l & 15, q = l >> 4;
  int wr = w >> 1, wc = w & 1;
  float* out = partial + (size_t)s * B_ * E_;
#pragma unroll
  for (int i = 0; i < 4; ++i)
#pragma unroll
    for (int j = 0; j < 2; ++j) {
      int col = bn0 + wc * 32 + j * 16 + m16;
#pragma unroll
      for (int r = 0; r < 4; ++r) {
        int row = bm0 + wr * 64 + i * 16 + q * 4 + r;
        out[(size_t)row * E_ + col] = acc[i][j][r];
      }
    }
}

// Reduce splits + bias + ReLU + bf16 cast + row inv-norm. Wave per row, no LDS.
__global__ __launch_bounds__(256) void gemm1_reduce(const float* __restrict__ partial,
                                                    const float* __restrict__ bias,
                                                    ushort_t* __restrict__ emb,
                                                    float* __restrict__ inv_emb) {
  int wv = threadIdx.x >> 6, l = threadIdx.x & 63;
  int row = blockIdx.x * 4 + wv;
  float sumsq = 0.f;
#pragma unroll
  for (int k = 0; k < 2; ++k) {
    int i = l + 64 * k;                     // floatx4 index within row (E/4 = 128)
    floatx4 v = {0.f, 0.f, 0.f, 0.f};
#pragma unroll
    for (int s = 0; s < SPLITK; ++s)
      v += ((const floatx4*)(partial + (size_t)s * B_ * E_ + (size_t)row * E_))[i];
    floatx4 bb = ((const floatx4*)bias)[i];
    ushort4_t o;
#pragma unroll
    for (int j = 0; j < 4; ++j) {
      float f = fmaxf(v[j] + bb[j], 0.f);
      o[j] = f2bf(f);
      float fb = bf2f(o[j]);                // norm of bf16-rounded emb (matches gemm2 input)
      sumsq += fb * fb;
    }
    ((ushort4_t*)(emb + (size_t)row * E_))[i] = o;
  }
  for (int off = 32; off; off >>= 1) sumsq += __shfl_down(sumsq, off);
  if (l == 0) inv_emb[row] = 1.f / fmaxf(sqrtf(sumsq), 1e-8f);
}

// GEMM2: n_e = (emb @ nw^T) * inv_emb[row] * inv_nw[col]; also fills p_e_stack.
// 128x256 tiles, waves 2x2 (wave tile 64x128), grid (32,16)=512.
__global__ __launch_bounds__(256, 2) void gemm2_kernel(const ushort_t* __restrict__ A,
                                                       const ushort_t* __restrict__ Bt,
                                                       const float* __restrict__ inv_a,
                                                       const float* __restrict__ inv_b,
                                                       const float* __restrict__ pe,
                                                       float* __restrict__ out) {
  __shared__ __align__(16) ushort_t As[128 * 64];
  __shared__ __align__(16) ushort_t Bs[256 * 64];
  floatx4 acc[4][8] = {};
  int bm0 = blockIdx.y * 128, bn0 = blockIdx.x * 256;
  gemm_core<128, 256, 64, 2, 4, 8>(A, Bt, E_, 0, E_, bm0, bn0, As, Bs, acc);
  int tid = threadIdx.x, w = tid >> 6, l = tid & 63, m16 = l & 15, q = l >> 4;
  int wr = w >> 1, wc = w & 1;
  float* out2 = out + (size_t)B_ * N_;
  float ibv[8];
#pragma unroll
  for (int j = 0; j < 8; ++j) ibv[j] = inv_b[bn0 + wc * 128 + j * 16 + m16];
#pragma unroll
  for (int i = 0; i < 4; ++i)
#pragma unroll
    for (int r = 0; r < 4; ++r) {
      int row = bm0 + wr * 64 + i * 16 + q * 4 + r;
      float ia = inv_a[row];
      float pv = pe[row];
      size_t base = (size_t)row * N_ + bn0 + wc * 128 + m16;
#pragma unroll
      for (int j = 0; j < 8; ++j) {
        out[base + j * 16]  = acc[i][j][r] * ia * ibv[j];
        out2[base + j * 16] = pv;
      }
    }
}

extern "C" void kernel_launch(void* const* d_in, const int* in_sizes, int n_in,
                              void* d_out, int out_size, void* d_ws, size_t ws_size,
                              hipStream_t stream) {
  (void)in_sizes; (void)n_in; (void)out_size; (void)ws_size;
  const float* vf    = (const float*)d_in[0];
  const float* p_wfs = (const float*)d_in[1];
  const float* n_wfs = (const float*)d_in[2];
  const float* gamma = (const float*)d_in[3];
  const float* beta  = (const float*)d_in[4];
  const float* W     = (const float*)d_in[5];
  const float* bias  = (const float*)d_in[6];
  float* out = (float*)d_out;

  char* ws = (char*)d_ws;
  float* psum    = (float*)ws;  ws += (size_t)64 * D_ * 4;
  float* psq     = (float*)ws;  ws += (size_t)64 * D_ * 4;
  float* scale   = (float*)ws;  ws += (size_t)D_ * 4;
  float* shift   = (float*)ws;  ws += (size_t)D_ * 4;
  float* pe      = (float*)ws;  ws += (size_t)B_ * 4;
  float* inv_nw  = (float*)ws;  ws += (size_t)N_ * 4;
  float* inv_emb = (float*)ws;  ws += (size_t)B_ * 4;
  float* partial = (float*)ws;  ws += (size_t)SPLITK * B_ * E_ * 4;
  ushort_t* vfn  = (ushort_t*)ws;  ws += (size_t)B_ * D_ * 2;
  ushort_t* wb   = (ushort_t*)ws;  ws += (size_t)E_ * D_ * 2;
  ushort_t* nwb  = (ushort_t*)ws;  ws += (size_t)N_ * E_ * 2;
  ushort_t* emb  = (ushort_t*)ws;  ws += (size_t)B_ * E_ * 2;

  bn_partial<<<dim3(D_ / 1024, 64), 256, 0, stream>>>(vf, psum, psq);
  bn_finalize<<<D_ / 1024, 256, 0, stream>>>(psum, psq, gamma, beta, scale, shift);
  pe_cast<<<B_ / 4, 256, 0, stream>>>(vf, p_wfs, scale, shift, vfn, pe);
  prep_kernel<<<2048 + N_ / 4, 256, 0, stream>>>(W, n_wfs, wb, nwb, inv_nw);
  gemm1_splitk<<<dim3(E_ / 64, B_ / 128, SPLITK), 256, 0, stream>>>(vfn, wb, partial);
  gemm1_reduce<<<B_ / 4, 256, 0, stream>>>(partial, bias, emb, inv_emb);
  gemm2_kernel<<<dim3(N_ / 256, B_ / 128), 256, 0, stream>>>(emb, nwb, inv_emb, inv_nw, pe, out);
}

// Round 5
// 272.164 us; speedup vs baseline: 1.0797x; 1.0338x over previous
//
#include <hip/hip_runtime.h>
#include <stdint.h>
#include <stddef.h>

#define B_ 2048
#define D_ 4096
#define E_ 512
#define N_ 8192
#define SPLITK 4

typedef unsigned short ushort_t;
typedef __attribute__((ext_vector_type(8))) short short8;
typedef __attribute__((ext_vector_type(4))) float floatx4;
typedef __attribute__((ext_vector_type(4))) unsigned short ushort4_t;

__device__ __forceinline__ void async_load16(const void* g, void* l) {
  __builtin_amdgcn_global_load_lds((__attribute__((address_space(1))) void*)(g),
                                   (__attribute__((address_space(3))) void*)(l), 16, 0, 0);
}

__device__ __forceinline__ ushort_t f2bf(float f) {
  unsigned int u = __float_as_uint(f);
  unsigned int r = (u + 0x7fffu + ((u >> 16) & 1u)) >> 16;
  return (ushort_t)r;
}
__device__ __forceinline__ float bf2f(ushort_t h) {
  return __uint_as_float(((unsigned int)h) << 16);
}

// ---------------- BatchNorm partial stats (float4) ----------------
__global__ __launch_bounds__(256) void bn_partial(const float* __restrict__ vf,
                                                  float* __restrict__ psum,
                                                  float* __restrict__ psq) {
  int d4 = blockIdx.x * 256 + threadIdx.x;
  int chunk = blockIdx.y;
  floatx4 s = {0.f, 0.f, 0.f, 0.f}, q = {0.f, 0.f, 0.f, 0.f};
  int r0 = chunk * 32;
  for (int r = r0; r < r0 + 32; ++r) {
    floatx4 v = ((const floatx4*)(vf + (size_t)r * D_))[d4];
    s += v; q += v * v;
  }
  ((floatx4*)(psum + (size_t)chunk * D_))[d4] = s;
  ((floatx4*)(psq  + (size_t)chunk * D_))[d4] = q;
}

// ---------------- prep: bn finalize + W cast + n_wfs cast/norms (3-way fused) ----------------
// blocks [0,4): bn finalize; [4,2052): W cast; [2052,4100): n_wfs (wave per row).
__global__ __launch_bounds__(256) void prep_all(const float* __restrict__ psum,
                                                const float* __restrict__ psq,
                                                const float* __restrict__ gamma,
                                                const float* __restrict__ beta,
                                                const float* __restrict__ W,
                                                const float* __restrict__ nw,
                                                float* __restrict__ scale,
                                                float* __restrict__ shift,
                                                ushort_t* __restrict__ wb,
                                                ushort_t* __restrict__ nwb,
                                                float* __restrict__ inv_nw) {
  int bid = blockIdx.x;
  if (bid < 4) {
    int d4 = bid * 256 + threadIdx.x;   // 0..1023
    floatx4 s = {0.f, 0.f, 0.f, 0.f}, q = {0.f, 0.f, 0.f, 0.f};
    for (int c = 0; c < 64; ++c) {
      s += ((const floatx4*)(psum + (size_t)c * D_))[d4];
      q += ((const floatx4*)(psq  + (size_t)c * D_))[d4];
    }
    floatx4 g = ((const floatx4*)gamma)[d4];
    floatx4 bt = ((const floatx4*)beta)[d4];
    floatx4 sc, sh;
#pragma unroll
    for (int j = 0; j < 4; ++j) {
      float mean = s[j] * (1.0f / B_);
      float var  = q[j] * (1.0f / B_) - mean * mean;
      float scj  = g[j] * rsqrtf(var + 1e-5f);
      sc[j] = scj;
      sh[j] = bt[j] - mean * scj;
    }
    ((floatx4*)scale)[d4] = sc;
    ((floatx4*)shift)[d4] = sh;
  } else if (bid < 2052) {
    size_t i = ((size_t)(bid - 4) * 256 + threadIdx.x) * 4;
    floatx4 x = *(const floatx4*)(W + i);
    ushort4_t o;
#pragma unroll
    for (int j = 0; j < 4; ++j) o[j] = f2bf(x[j]);
    *(ushort4_t*)(wb + i) = o;
  } else {
    int wv = threadIdx.x >> 6, l = threadIdx.x & 63;
    int n = (bid - 2052) * 4 + wv;
    const floatx4* src = (const floatx4*)(nw + (size_t)n * E_);
    ushort4_t* dst = (ushort4_t*)(nwb + (size_t)n * E_);
    float s = 0.f;
#pragma unroll
    for (int k = 0; k < 2; ++k) {
      floatx4 x = src[l + 64 * k];
      ushort4_t o;
#pragma unroll
      for (int j = 0; j < 4; ++j) { o[j] = f2bf(x[j]); s += x[j] * x[j]; }
      dst[l + 64 * k] = o;
    }
    for (int off = 32; off; off >>= 1) s += __shfl_down(s, off);
    if (l == 0) inv_nw[n] = 1.f / fmaxf(sqrtf(s), 1e-8f);
  }
}

// ---------------- fused: p_e cosine + vfn bf16 cast (one wave per row) ----------------
__global__ __launch_bounds__(256) void pe_cast(const float* __restrict__ vf,
                                               const float* __restrict__ p,
                                               const float* __restrict__ scale,
                                               const float* __restrict__ shift,
                                               ushort_t* __restrict__ vfn,
                                               float* __restrict__ pe) {
  int wv = threadIdx.x >> 6, l = threadIdx.x & 63;
  int v = blockIdx.x * 4 + wv;
  const floatx4* vf4 = (const floatx4*)(vf + (size_t)v * D_);
  const floatx4* p4  = (const floatx4*)(p  + (size_t)v * D_);
  const floatx4* sc4 = (const floatx4*)scale;
  const floatx4* sh4 = (const floatx4*)shift;
  ushort_t* vrow = vfn + (size_t)v * D_;
  float sd = 0.f, sa = 0.f, sb = 0.f;
#pragma unroll 4
  for (int k = 0; k < 16; ++k) {
    int i = l + 64 * k;
    floatx4 x = vf4[i], y = p4[i], s = sc4[i], t = sh4[i];
    ushort4_t o;
#pragma unroll
    for (int j = 0; j < 4; ++j) {
      float xn = x[j] * s[j] + t[j];
      o[j] = f2bf(xn);
      sd += xn * y[j]; sa += xn * xn; sb += y[j] * y[j];
    }
    *(ushort4_t*)(vrow + i * 4) = o;
  }
  for (int off = 32; off; off >>= 1) {
    sd += __shfl_down(sd, off); sa += __shfl_down(sa, off); sb += __shfl_down(sb, off);
  }
  if (l == 0) {
    float na = fmaxf(sqrtf(sa), 1e-8f), nb = fmaxf(sqrtf(sb), 1e-8f);
    pe[v] = sd / (na * nb);
  }
}

// ---------------- MFMA gemm core (generic, used by gemm1) ----------------
// Verified gfx950 16x16x32 bf16 layout: a-frag A[m=lane&15][k=quad*8+j],
// b-frag Bt[n=lane&15][k=quad*8+j], C/D: col=lane&15, row=quad*4+reg.
template <int BM, int BN, int BK, int WCOLS, int MT, int NT>
__device__ __forceinline__ void gemm_core(const ushort_t* __restrict__ A,
                                          const ushort_t* __restrict__ Bt, int K,
                                          int kb, int ke, int bm0, int bn0,
                                          ushort_t* As, ushort_t* Bs,
                                          floatx4 (&acc)[MT][NT]) {
  const int tid = threadIdx.x, w = tid >> 6, l = tid & 63;
  constexpr int ISS_A = BM * BK / 2048;
  constexpr int ISS_B = BN * BK / 2048;
  const int wr = w / WCOLS, wc = w % WCOLS;
  const int m16 = l & 15, q = l >> 4;

  for (int k0 = kb; k0 < ke; k0 += BK) {
#pragma unroll
    for (int i = 0; i < ISS_A; ++i) {
      int e = i * 2048 + tid * 8;
      int row = e / BK, col = e % BK;
      async_load16(A + (size_t)(bm0 + row) * K + (k0 + col), &As[i * 2048 + w * 512]);
    }
#pragma unroll
    for (int i = 0; i < ISS_B; ++i) {
      int e = i * 2048 + tid * 8;
      int row = e / BK, col = e % BK;
      async_load16(Bt + (size_t)(bn0 + row) * K + (k0 + col), &Bs[i * 2048 + w * 512]);
    }
    __syncthreads();
#pragma unroll
    for (int kc = 0; kc < BK / 32; ++kc) {
      short8 af[MT], bf[NT];
#pragma unroll
      for (int i = 0; i < MT; ++i)
        af[i] = *(const short8*)&As[(wr * (MT * 16) + i * 16 + m16) * BK + kc * 32 + q * 8];
#pragma unroll
      for (int j = 0; j < NT; ++j)
        bf[j] = *(const short8*)&Bs[(wc * (NT * 16) + j * 16 + m16) * BK + kc * 32 + q * 8];
#pragma unroll
      for (int i = 0; i < MT; ++i)
#pragma unroll
        for (int j = 0; j < NT; ++j)
          acc[i][j] = __builtin_amdgcn_mfma_f32_16x16x32_bf16(af[i], bf[j], acc[i][j], 0, 0, 0);
    }
    __syncthreads();
  }
}

// GEMM1 split-K: partial[s] = vfn @ W^T over K-chunk s. 128x64 tiles, grid (8,16,4)=512.
__global__ __launch_bounds__(256, 2) void gemm1_splitk(const ushort_t* __restrict__ A,
                                                       const ushort_t* __restrict__ Bt,
                                                       float* __restrict__ partial) {
  __shared__ __align__(16) ushort_t As[128 * 64];
  __shared__ __align__(16) ushort_t Bs[64 * 64];
  floatx4 acc[4][2] = {};
  int bm0 = blockIdx.y * 128, bn0 = blockIdx.x * 64, s = blockIdx.z;
  int kb = s * (D_ / SPLITK);
  gemm_core<128, 64, 64, 2, 4, 2>(A, Bt, D_, kb, kb + D_ / SPLITK, bm0, bn0, As, Bs, acc);
  int tid = threadIdx.x, w = tid >> 6, l = tid & 63, m16 = l & 15, q = l >> 4;
  int wr = w >> 1, wc = w & 1;
  float* out = partial + (size_t)s * B_ * E_;
#pragma unroll
  for (int i = 0; i < 4; ++i)
#pragma unroll
    for (int j = 0; j < 2; ++j) {
      int col = bn0 + wc * 32 + j * 16 + m16;
#pragma unroll
      for (int r = 0; r < 4; ++r) {
        int row = bm0 + wr * 64 + i * 16 + q * 4 + r;
        out[(size_t)row * E_ + col] = acc[i][j][r];
      }
    }
}

// Reduce splits + bias + ReLU + bf16 cast + row inv-norm. Wave per row, no LDS.
__global__ __launch_bounds__(256) void gemm1_reduce(const float* __restrict__ partial,
                                                    const float* __restrict__ bias,
                                                    ushort_t* __restrict__ emb,
                                                    float* __restrict__ inv_emb) {
  int wv = threadIdx.x >> 6, l = threadIdx.x & 63;
  int row = blockIdx.x * 4 + wv;
  float sumsq = 0.f;
#pragma unroll
  for (int k = 0; k < 2; ++k) {
    int i = l + 64 * k;
    floatx4 v = {0.f, 0.f, 0.f, 0.f};
#pragma unroll
    for (int s = 0; s < SPLITK; ++s)
      v += ((const floatx4*)(partial + (size_t)s * B_ * E_ + (size_t)row * E_))[i];
    floatx4 bb = ((const floatx4*)bias)[i];
    ushort4_t o;
#pragma unroll
    for (int j = 0; j < 4; ++j) {
      float f = fmaxf(v[j] + bb[j], 0.f);
      o[j] = f2bf(f);
      float fb = bf2f(o[j]);
      sumsq += fb * fb;
    }
    ((ushort4_t*)(emb + (size_t)row * E_))[i] = o;
  }
  for (int off = 32; off; off >>= 1) sumsq += __shfl_down(sumsq, off);
  if (l == 0) inv_emb[row] = 1.f / fmaxf(sqrtf(sumsq), 1e-8f);
}

// GEMM2: n_e = (emb @ nw^T) * inv_emb[row] * inv_nw[col].
// 128x128 tiles, grid (64,16)=1024, waves 2x2 (wave tile 64x64, MT=NT=4).
// p_e_stack (out2) stores are interleaved into the K-loop: out2 depends only on
// pe[row], so its 67 MB of writes drain to L2 during MFMA compute instead of
// doubling the end-of-kernel write burst.
__global__ __launch_bounds__(256, 2) void gemm2_kernel(const ushort_t* __restrict__ A,
                                                       const ushort_t* __restrict__ Bt,
                                                       const float* __restrict__ inv_a,
                                                       const float* __restrict__ inv_b,
                                                       const float* __restrict__ pe,
                                                       float* __restrict__ out) {
  __shared__ __align__(16) ushort_t As[128 * 64];
  __shared__ __align__(16) ushort_t Bs[128 * 64];
  floatx4 acc[4][4] = {};
  const int tid = threadIdx.x, w = tid >> 6, l = tid & 63;
  const int m16 = l & 15, q = l >> 4;
  const int wr = w >> 1, wc = w & 1;
  const int bm0 = blockIdx.y * 128, bn0 = blockIdx.x * 128;

  // prefetch pe for the 16 rows this lane covers
  float pv[4][4];
#pragma unroll
  for (int i = 0; i < 4; ++i)
#pragma unroll
    for (int r = 0; r < 4; ++r)
      pv[i][r] = pe[bm0 + wr * 64 + i * 16 + q * 4 + r];
  float* out2lane = out + (size_t)B_ * N_ + bn0 + wc * 64 + m16;

#pragma unroll
  for (int it = 0; it < E_ / 64; ++it) {   // 8 iterations
    int k0 = it * 64;
#pragma unroll
    for (int i = 0; i < 4; ++i) {
      int e = i * 2048 + tid * 8;
      async_load16(A + (size_t)(bm0 + e / 64) * E_ + (k0 + e % 64), &As[i * 2048 + w * 512]);
    }
#pragma unroll
    for (int i = 0; i < 4; ++i) {
      int e = i * 2048 + tid * 8;
      async_load16(Bt + (size_t)(bn0 + e / 64) * E_ + (k0 + e % 64), &Bs[i * 2048 + w * 512]);
    }
    __syncthreads();
    // interleaved p_e_stack stores: 8 of this lane's 64 outputs per iteration
#pragma unroll
    for (int t = 0; t < 8; ++t) {
      int idx = it * 8 + t;
      int i = idx >> 4, r = (idx >> 2) & 3, j = idx & 3;
      int row = bm0 + wr * 64 + i * 16 + q * 4 + r;
      out2lane[(size_t)row * N_ + j * 16] = pv[i][r];
    }
#pragma unroll
    for (int kc = 0; kc < 2; ++kc) {
      short8 af[4], bf[4];
#pragma unroll
      for (int i = 0; i < 4; ++i)
        af[i] = *(const short8*)&As[(wr * 64 + i * 16 + m16) * 64 + kc * 32 + q * 8];
#pragma unroll
      for (int j = 0; j < 4; ++j)
        bf[j] = *(const short8*)&Bs[(wc * 64 + j * 16 + m16) * 64 + kc * 32 + q * 8];
#pragma unroll
      for (int i = 0; i < 4; ++i)
#pragma unroll
        for (int j = 0; j < 4; ++j)
          acc[i][j] = __builtin_amdgcn_mfma_f32_16x16x32_bf16(af[i], bf[j], acc[i][j], 0, 0, 0);
    }
    __syncthreads();
  }

  float ibv[4];
#pragma unroll
  for (int j = 0; j < 4; ++j) ibv[j] = inv_b[bn0 + wc * 64 + j * 16 + m16];
#pragma unroll
  for (int i = 0; i < 4; ++i)
#pragma unroll
    for (int r = 0; r < 4; ++r) {
      int row = bm0 + wr * 64 + i * 16 + q * 4 + r;
      float ia = inv_a[row];
      size_t base = (size_t)row * N_ + bn0 + wc * 64 + m16;
#pragma unroll
      for (int j = 0; j < 4; ++j)
        out[base + j * 16] = acc[i][j][r] * ia * ibv[j];
    }
}

extern "C" void kernel_launch(void* const* d_in, const int* in_sizes, int n_in,
                              void* d_out, int out_size, void* d_ws, size_t ws_size,
                              hipStream_t stream) {
  (void)in_sizes; (void)n_in; (void)out_size; (void)ws_size;
  const float* vf    = (const float*)d_in[0];
  const float* p_wfs = (const float*)d_in[1];
  const float* n_wfs = (const float*)d_in[2];
  const float* gamma = (const float*)d_in[3];
  const float* beta  = (const float*)d_in[4];
  const float* W     = (const float*)d_in[5];
  const float* bias  = (const float*)d_in[6];
  float* out = (float*)d_out;

  char* ws = (char*)d_ws;
  float* psum    = (float*)ws;  ws += (size_t)64 * D_ * 4;
  float* psq     = (float*)ws;  ws += (size_t)64 * D_ * 4;
  float* scale   = (float*)ws;  ws += (size_t)D_ * 4;
  float* shift   = (float*)ws;  ws += (size_t)D_ * 4;
  float* pe      = (float*)ws;  ws += (size_t)B_ * 4;
  float* inv_nw  = (float*)ws;  ws += (size_t)N_ * 4;
  float* inv_emb = (float*)ws;  ws += (size_t)B_ * 4;
  float* partial = (float*)ws;  ws += (size_t)SPLITK * B_ * E_ * 4;
  ushort_t* vfn  = (ushort_t*)ws;  ws += (size_t)B_ * D_ * 2;
  ushort_t* wb   = (ushort_t*)ws;  ws += (size_t)E_ * D_ * 2;
  ushort_t* nwb  = (ushort_t*)ws;  ws += (size_t)N_ * E_ * 2;
  ushort_t* emb  = (ushort_t*)ws;  ws += (size_t)B_ * E_ * 2;

  bn_partial<<<dim3(D_ / 1024, 64), 256, 0, stream>>>(vf, psum, psq);
  prep_all<<<4 + 2048 + N_ / 4, 256, 0, stream>>>(psum, psq, gamma, beta, W, n_wfs,
                                                  scale, shift, wb, nwb, inv_nw);
  pe_cast<<<B_ / 4, 256, 0, stream>>>(vf, p_wfs, scale, shift, vfn, pe);
  gemm1_splitk<<<dim3(E_ / 64, B_ / 128, SPLITK), 256, 0, stream>>>(vfn, wb, partial);
  gemm1_reduce<<<B_ / 4, 256, 0, stream>>>(partial, bias, emb, inv_emb);
  gemm2_kernel<<<dim3(N_ / 128, B_ / 128), 256, 0, stream>>>(emb, nwb, inv_emb, inv_nw, pe, out);
}